// Round 5
// baseline (167.433 us; speedup 1.0000x reference)
//
#include <hip/hip_runtime.h>
#include <math.h>

#define XYD 16
#define ZD 16
#define SS 4096
#define VV 2048
#define BB 8
#define LL 32
#define WW 8
#define VC 32          // v-chunk for smoothing kernel
#define SM_STRIDE 257  // LDS tile stride (states dim +1 pad)
#define NE (BB * LL * WW)   // 2048 story entries
#define HL 256              // hit-list capacity (expected ~32 hits, 40 sigma margin)

#define GUARD_L 16
#define GUARD_R 512
#define EBUF_N (GUARD_L + SS + GUARD_R)  // bf16 elems per buffer

__device__ __forceinline__ float b2f(unsigned short u) {
    union { unsigned int i; float f; } x; x.i = ((unsigned int)u) << 16; return x.f;
}
__device__ __forceinline__ unsigned short f2b(float f) {
    union { float f; unsigned int i; } x; x.f = f; return (unsigned short)(x.i >> 16);
}

// ---------------- Kernel 1: logZ[s] = logsumexp over V; also zero all_emis -----------
__global__ void k_logZ(const float* __restrict__ emis_w, float* __restrict__ logZ,
                       float4* __restrict__ all_emis4) {
    // zero 4 MB of all_emis: 1024 blocks * 256 threads * 16 B
    float4 z4 = {0.f, 0.f, 0.f, 0.f};
    all_emis4[blockIdx.x * 256 + threadIdx.x] = z4;

    int wave = threadIdx.x >> 6;
    int lane = threadIdx.x & 63;
    int row  = blockIdx.x * 4 + wave;
    const float* r = emis_w + (size_t)row * VV;
    float vals[32];
    float m = -INFINITY;
#pragma unroll
    for (int k = 0; k < 8; k++) {
        float4 f = ((const float4*)r)[k * 64 + lane];
        vals[k*4+0] = f.x; vals[k*4+1] = f.y; vals[k*4+2] = f.z; vals[k*4+3] = f.w;
    }
#pragma unroll
    for (int k = 0; k < 32; k++) m = fmaxf(m, vals[k]);
#pragma unroll
    for (int o = 32; o; o >>= 1) m = fmaxf(m, __shfl_xor(m, o));
    float sum = 0.f;
#pragma unroll
    for (int k = 0; k < 32; k++) sum += __expf(vals[k] - m);
#pragma unroll
    for (int o = 32; o; o >>= 1) sum += __shfl_xor(sum, o);
    if (lane == 0) logZ[row] = m + __logf(sum);
}

// ---------------- Kernel 2: fused smoothing + emission scatter -----------------------
// Block (z, vchunk): build smoothed tile [VC x 256] in LDS, then for each story entry
// whose token lies in this chunk, atomically accumulate the 256-state column into
// all_emis[t,b, z*256 .. z*256+255].  smT never touches memory.
__global__ void __launch_bounds__(256) k_smooth_emis(
    const float* __restrict__ emis_w, const float* __restrict__ logZ,
    const int* __restrict__ stories, float* __restrict__ all_emis) {
    __shared__ float tileT[VC * SM_STRIDE];   // input probs  [v][state]
    __shared__ float smtile[VC * SM_STRIDE];  // smoothed log [v][state]
    __shared__ int   toks[NE];
    __shared__ int   hitlist[HL];
    __shared__ int   nhits;
    int z  = blockIdx.x;
    int v0 = blockIdx.y * VC;
    int tid = threadIdx.x;

    if (tid == 0) nhits = 0;
#pragma unroll
    for (int i = 0; i < NE / 256; i++) toks[i * 256 + tid] = stories[i * 256 + tid];

    int rsub = tid >> 3;        // 0..31
    int c0   = (tid & 7) * 4;   // 0,4,..,28
#pragma unroll
    for (int it = 0; it < 8; it++) {
        int r  = it * 32 + rsub;         // plane state 0..255
        int sg = z * 256 + r;
        float lz = logZ[sg];
        float4 w = *(const float4*)(emis_w + (size_t)sg * VV + v0 + c0);
        tileT[(c0+0)*SM_STRIDE + r] = __expf(w.x - lz);
        tileT[(c0+1)*SM_STRIDE + r] = __expf(w.y - lz);
        tileT[(c0+2)*SM_STRIDE + r] = __expf(w.z - lz);
        tileT[(c0+3)*SM_STRIDE + r] = __expf(w.w - lz);
    }
    __syncthreads();

    // scan story entries for tokens in [v0, v0+VC)
    for (int e = tid; e < NE; e += 256) {
        unsigned d = (unsigned)(toks[e] - v0);
        if (d < VC) {
            int k = atomicAdd(&nhits, 1);
            if (k < HL) hitlist[k] = e;
        }
    }

    // smoothing (identical math to prior rounds)
    int x = tid & 15, y = tid >> 4;
    int sxp = (x < 15) ? tid + 1  : tid;
    int sxm = (x > 0)  ? tid - 1  : tid;
    int syp = (y < 15) ? tid + 16 : tid;
    int sym = (y > 0)  ? tid - 16 : tid;
#pragma unroll
    for (int i = 0; i < VC; i++) {
        const float* tb = tileT + i * SM_STRIDE;
        float s = tb[tid] + tb[sxp] + tb[sxm] + tb[syp] + tb[sym];
        smtile[i * SM_STRIDE + tid] = __logf(s * 0.2f);
    }
    __syncthreads();

    int nh = nhits; if (nh > HL) nh = HL;
    float* dst0 = all_emis + z * 256 + tid;
    for (int h = 0; h < nh; h++) {
        int e = hitlist[h];
        int tok = toks[e] - v0;
        int bb  = e / (LL * WW);
        int tt  = (e / WW) % LL;
        atomicAdd(dst0 + ((size_t)tt * BB + bb) * SS, smtile[tok * SM_STRIDE + tid]);
    }
}

// ---------------- Kernel 3: forward recurrence ---------------------------------------
// One block per batch; 1024 threads, 4 consecutive states/thread.
// Predicted global frame Xp_t = 2*g_{t-1} - g_{t-2} (g = v[state 0], no reduction).
// bf16 Ebuf; out-store pipelined one step behind (ack drains across the next step).
__global__ void __launch_bounds__(1024) k_forward(
    const float* __restrict__ trans_w, const float* __restrict__ prior_w,
    const float* __restrict__ all_emis, float* __restrict__ out) {
    __shared__ __align__(16) unsigned short Ebuf[2][EBUF_N];
    __shared__ float red2[2];
    __shared__ float pr[16];
    int b = blockIdx.x;
    int tid = threadIdx.x;
    int lane = tid & 63, wid = tid >> 6;

    if (tid < GUARD_L) { Ebuf[0][tid] = 0; Ebuf[1][tid] = 0; }
    if (tid < GUARD_R) {
        Ebuf[0][GUARD_L + SS + tid] = 0;
        Ebuf[1][GUARD_L + SS + tid] = 0;
    }

    // ---- transition prologue: pw (geometric order), am per state ----
    float pw[28], am[4];
    {
        float w7[28];
        const float4* t4 = (const float4*)(trans_w + (size_t)tid * 28);
#pragma unroll
        for (int k = 0; k < 7; k++) ((float4*)w7)[k] = t4[k];
#pragma unroll
        for (int i = 0; i < 4; i++) {
            int j = tid * 4 + i;
            int xx = j & 15, yy = (j >> 4) & 15, zz = j >> 8;
            bool val[7];
            val[0] = true;
            val[1] = (xx < 15); val[2] = (xx > 0);
            val[3] = (yy < 15); val[4] = (yy > 0);
            val[5] = (zz < 15); val[6] = (zz < 14);
            const float* rw = w7 + i * 7;
            float w[7]; int cnt = 0; float m = -INFINITY;
#pragma unroll
            for (int d = 0; d < 7; d++) { if (val[d]) { w[d] = rw[cnt++]; m = fmaxf(m, w[d]); } }
            float se = 0.f;
#pragma unroll
            for (int d = 0; d < 7; d++) if (val[d]) se += __expf(w[d] - m);
#pragma unroll
            for (int d = 0; d < 7; d++) pw[i*7+d] = val[d] ? __expf(w[d] - m) : 0.f;
            am[i] = -__logf(se);
        }
    }

    float4 pv = ((const float4*)prior_w)[tid];
    const float4* emp = (const float4*)(all_emis + (size_t)b * SS) + tid;
    float4 em = *emp;   // t=0

    // ---- priors log-softmax denominator ----
    float lm = fmaxf(fmaxf(pv.x, pv.y), fmaxf(pv.z, pv.w));
#pragma unroll
    for (int o = 32; o; o >>= 1) lm = fmaxf(lm, __shfl_xor(lm, o));
    if (lane == 0) pr[wid] = lm;
    __syncthreads();
    float gm = pr[0];
#pragma unroll
    for (int w = 1; w < 16; w++) gm = fmaxf(gm, pr[w]);
    __syncthreads();
    float ls = __expf(pv.x - gm) + __expf(pv.y - gm) + __expf(pv.z - gm) + __expf(pv.w - gm);
#pragma unroll
    for (int o = 32; o; o >>= 1) ls += __shfl_xor(ls, o);
    if (lane == 0) pr[wid] = ls;
    __syncthreads();
    float gs = 0.f;
#pragma unroll
    for (int w = 0; w < 16; w++) gs += pr[w];
    float logZp = gm + __logf(gs);

    // ---- step 0 (store deferred) ----
    float v0 = em.x + pv.x - logZp;
    float v1 = em.y + pv.y - logZp;
    float v2 = em.z + pv.z - logZp;
    float v3 = em.w + pv.w - logZp;
    float4 ov_prev = {v0, v1, v2, v3};
    float4* outp = (float4*)(out + (size_t)b * SS) + tid;  // slot for t=0

    if (tid == 0) red2[0] = v0;   // g_0
    __syncthreads();
    float g1 = red2[0];
    float XpPrev = g1;
    float Erx = __expf(v0 - XpPrev), Ery = __expf(v1 - XpPrev);
    float Erz = __expf(v2 - XpPrev), Erw = __expf(v3 - XpPrev);
    {
        ushort4 E;
        E.x = f2b(Erx); E.y = f2b(Ery); E.z = f2b(Erz); E.w = f2b(Erw);
        *(ushort4*)(&Ebuf[0][GUARD_L + 4 * tid]) = E;
    }

    emp += (BB * SS) / 4;
    float4 em_next = *emp;   // t=1

    // ---- steps 1..L-1: one barrier per step; out-store pipelined one step back ----
    int cur = 0;
    for (int t = 1; t < LL; t++) {
        __syncthreads();
        *outp = ov_prev;                    // store v_{t-1}; ack drains over this step
        outp += (BB * SS) / 4;

        em = em_next;
        if (t < LL - 1) { emp += (BB * SS) / 4; em_next = *emp; }

        float g0 = red2[cur];
        float Xp = 2.f * g0 - g1;

        const unsigned short* Eb = Ebuf[cur] + GUARD_L + 4 * tid;
        ushort4 YpU = *(const ushort4*)(Eb + 16);
        ushort4 YmU = *(const ushort4*)(Eb - 16);
        ushort4 ZpU = *(const ushort4*)(Eb + 256);
        ushort4 ZqU = *(const ushort4*)(Eb + 512);
        float bx  = b2f(Eb[4]);
        float cxw = b2f(Eb[-1]);

        float a0 = Erx*pw[0]  + Ery*pw[1]  + cxw*pw[2]  + b2f(YpU.x)*pw[3]  + b2f(YmU.x)*pw[4]  + b2f(ZpU.x)*pw[5]  + b2f(ZqU.x)*pw[6];
        float a1 = Ery*pw[7]  + Erz*pw[8]  + Erx*pw[9]  + b2f(YpU.y)*pw[10] + b2f(YmU.y)*pw[11] + b2f(ZpU.y)*pw[12] + b2f(ZqU.y)*pw[13];
        float a2 = Erz*pw[14] + Erw*pw[15] + Ery*pw[16] + b2f(YpU.z)*pw[17] + b2f(YmU.z)*pw[18] + b2f(ZpU.z)*pw[19] + b2f(ZqU.z)*pw[20];
        float a3 = Erw*pw[21] + bx*pw[22]  + Erz*pw[23] + b2f(YpU.w)*pw[24] + b2f(YmU.w)*pw[25] + b2f(ZpU.w)*pw[26] + b2f(ZqU.w)*pw[27];

        v0 = em.x + __logf(a0) + XpPrev + am[0];
        v1 = em.y + __logf(a1) + XpPrev + am[1];
        v2 = em.z + __logf(a2) + XpPrev + am[2];
        v3 = em.w + __logf(a3) + XpPrev + am[3];
        ov_prev.x = v0; ov_prev.y = v1; ov_prev.z = v2; ov_prev.w = v3;

        Erx = __expf(v0 - Xp); Ery = __expf(v1 - Xp);
        Erz = __expf(v2 - Xp); Erw = __expf(v3 - Xp);
        {
            ushort4 E;
            E.x = f2b(Erx); E.y = f2b(Ery); E.z = f2b(Erz); E.w = f2b(Erw);
            *(ushort4*)(&Ebuf[cur ^ 1][GUARD_L + 4 * tid]) = E;
        }
        if (tid == 0) red2[cur ^ 1] = v0;  // g_t

        g1 = g0; XpPrev = Xp; cur ^= 1;
    }
    *outp = ov_prev;   // t = LL-1
}

extern "C" void kernel_launch(void* const* d_in, const int* in_sizes, int n_in,
                              void* d_out, int out_size, void* d_ws, size_t ws_size,
                              hipStream_t stream) {
    const int*   stories = (const int*)d_in[0];
    const float* trans_w = (const float*)d_in[2];
    const float* emis_w  = (const float*)d_in[3];
    const float* prior_w = (const float*)d_in[4];
    float* out = (float*)d_out;

    char* ws = (char*)d_ws;
    float* all_emis = (float*)(ws);                                   // 4 MB
    float* logZ     = (float*)(ws + (size_t)LL * BB * SS * 4);        // 16 KB

    k_logZ<<<SS / 4, 256, 0, stream>>>(emis_w, logZ, (float4*)all_emis);
    k_smooth_emis<<<dim3(ZD, VV / VC), 256, 0, stream>>>(emis_w, logZ, stories, all_emis);
    k_forward<<<BB, 1024, 0, stream>>>(trans_w, prior_w, all_emis, out);
}

// Round 7
// 156.464 us; speedup vs baseline: 1.0701x; 1.0701x over previous
//
#include <hip/hip_runtime.h>
#include <math.h>

#define XYD 16
#define ZD 16
#define SS 4096
#define VV 2048
#define BB 8
#define LL 32
#define WW 8
#define VC 32          // v-chunk for smoothing kernel
#define SM_STRIDE 257  // LDS tile stride (states dim +1 pad)

#define GUARD_L 16
#define GUARD_R 512
#define EBUF_N (GUARD_L + SS + GUARD_R)  // bf16 elems per buffer

// Raw workgroup barrier: LDS ordering only (no vmcnt drain of global store acks /
// prefetch loads). DS ops complete in-order per wave; lgkmcnt(0) before s_barrier
// is the minimal correct LDS producer->consumer sync.
#define BAR() asm volatile("s_waitcnt lgkmcnt(0)\n\ts_barrier" ::: "memory")

__device__ __forceinline__ float b2f(unsigned short u) {
    union { unsigned int i; float f; } x; x.i = ((unsigned int)u) << 16; return x.f;
}
__device__ __forceinline__ unsigned short f2b(float f) {
    union { float f; unsigned int i; } x; x.f = f; return (unsigned short)(x.i >> 16);
}

// ---------------- Kernel 1: logZ[s] = logsumexp over V of emis_w[s,:] ----------------
__global__ void k_logZ(const float* __restrict__ emis_w, float* __restrict__ logZ) {
    int wave = threadIdx.x >> 6;
    int lane = threadIdx.x & 63;
    int row  = blockIdx.x * 4 + wave;
    const float* r = emis_w + (size_t)row * VV;
    float vals[32];
    float m = -INFINITY;
#pragma unroll
    for (int k = 0; k < 8; k++) {
        float4 f = ((const float4*)r)[k * 64 + lane];
        vals[k*4+0] = f.x; vals[k*4+1] = f.y; vals[k*4+2] = f.z; vals[k*4+3] = f.w;
    }
#pragma unroll
    for (int k = 0; k < 32; k++) m = fmaxf(m, vals[k]);
#pragma unroll
    for (int o = 32; o; o >>= 1) m = fmaxf(m, __shfl_xor(m, o));
    float sum = 0.f;
#pragma unroll
    for (int k = 0; k < 32; k++) sum += __expf(vals[k] - m);
#pragma unroll
    for (int o = 32; o; o >>= 1) sum += __shfl_xor(sum, o);
    if (lane == 0) logZ[row] = m + __logf(sum);
}

// ---------------- Kernel 2: smoothing + transpose ------------------------------------
__global__ void k_smooth(const float* __restrict__ emis_w, const float* __restrict__ logZ,
                         float* __restrict__ smT) {
    __shared__ float tileT[VC * SM_STRIDE];  // [v][state]
    int z  = blockIdx.x;
    int v0 = blockIdx.y * VC;
    int tid = threadIdx.x;
    int rsub = tid >> 3;        // 0..31
    int c0   = (tid & 7) * 4;   // 0,4,..,28

#pragma unroll
    for (int it = 0; it < 8; it++) {
        int r  = it * 32 + rsub;         // plane state 0..255
        int sg = z * 256 + r;
        float lz = logZ[sg];
        float4 w = *(const float4*)(emis_w + (size_t)sg * VV + v0 + c0);
        tileT[(c0+0)*SM_STRIDE + r] = __expf(w.x - lz);
        tileT[(c0+1)*SM_STRIDE + r] = __expf(w.y - lz);
        tileT[(c0+2)*SM_STRIDE + r] = __expf(w.z - lz);
        tileT[(c0+3)*SM_STRIDE + r] = __expf(w.w - lz);
    }
    __syncthreads();

    int x = tid & 15, y = tid >> 4;
    int sxp = (x < 15) ? tid + 1  : tid;
    int sxm = (x > 0)  ? tid - 1  : tid;
    int syp = (y < 15) ? tid + 16 : tid;
    int sym = (y > 0)  ? tid - 16 : tid;
    float* o = smT + (size_t)v0 * SS + z * 256 + tid;
#pragma unroll
    for (int i = 0; i < VC; i++) {
        const float* tb = tileT + i * SM_STRIDE;
        float s = tb[tid] + tb[sxp] + tb[sxm] + tb[syp] + tb[sym];
        o[(size_t)i * SS] = __logf(s * 0.2f);
    }
}

// ---------------- Kernel 3: all_emis[t,b,s] = sum_w smoothedT[tok][s] (float4) -------
__global__ void k_emis(const int* __restrict__ stories, const float* __restrict__ smT,
                       float* __restrict__ all_emis) {
    int blk = blockIdx.x;
    int t = blk >> 3, b = blk & 7;
    int tid = threadIdx.x;
    int tok[WW];
#pragma unroll
    for (int w = 0; w < WW; w++) tok[w] = stories[(b * LL + t) * WW + w];
#pragma unroll
    for (int i = 0; i < 4; i++) {
        int s = i * 1024 + tid * 4;
        float4 acc = {0.f, 0.f, 0.f, 0.f};
#pragma unroll
        for (int w = 0; w < WW; w++) {
            if (tok[w] < VV) {  // wave-uniform
                float4 f = *(const float4*)(smT + (size_t)tok[w] * SS + s);
                acc.x += f.x; acc.y += f.y; acc.z += f.z; acc.w += f.w;
            }
        }
        *(float4*)(all_emis + ((size_t)t * BB + b) * SS + s) = acc;
    }
}

// ---------------- Kernel 4: forward recurrence ---------------------------------------
// One block per batch; 1024 threads, 4 consecutive states/thread.
// Predicted global frame Xp_t = 2*g_{t-1} - g_{t-2} (g = v[state 0], no reduction).
// bf16 Ebuf; raw lgkmcnt-only barrier in the loop (no vmcnt drain of store acks).
__global__ void __launch_bounds__(1024) k_forward(
    const float* __restrict__ trans_w, const float* __restrict__ prior_w,
    const float* __restrict__ all_emis, float* __restrict__ out) {
    __shared__ __align__(16) unsigned short Ebuf[2][EBUF_N];
    __shared__ float red2[2];
    __shared__ float pr[16];
    int b = blockIdx.x;
    int tid = threadIdx.x;
    int lane = tid & 63, wid = tid >> 6;

    if (tid < GUARD_L) { Ebuf[0][tid] = 0; Ebuf[1][tid] = 0; }
    if (tid < GUARD_R) {
        Ebuf[0][GUARD_L + SS + tid] = 0;
        Ebuf[1][GUARD_L + SS + tid] = 0;
    }

    // ---- transition prologue: pw (geometric order), am per state ----
    float pw[28], am[4];
    {
        float w7[28];
        const float4* t4 = (const float4*)(trans_w + (size_t)tid * 28);
#pragma unroll
        for (int k = 0; k < 7; k++) ((float4*)w7)[k] = t4[k];
#pragma unroll
        for (int i = 0; i < 4; i++) {
            int j = tid * 4 + i;
            int xx = j & 15, yy = (j >> 4) & 15, zz = j >> 8;
            bool val[7];
            val[0] = true;
            val[1] = (xx < 15); val[2] = (xx > 0);
            val[3] = (yy < 15); val[4] = (yy > 0);
            val[5] = (zz < 15); val[6] = (zz < 14);
            const float* rw = w7 + i * 7;
            float w[7]; int cnt = 0; float m = -INFINITY;
#pragma unroll
            for (int d = 0; d < 7; d++) { if (val[d]) { w[d] = rw[cnt++]; m = fmaxf(m, w[d]); } }
            float se = 0.f;
#pragma unroll
            for (int d = 0; d < 7; d++) if (val[d]) se += __expf(w[d] - m);
#pragma unroll
            for (int d = 0; d < 7; d++) pw[i*7+d] = val[d] ? __expf(w[d] - m) : 0.f;
            am[i] = -__logf(se);
        }
    }

    float4 pv = ((const float4*)prior_w)[tid];
    const float4* emp = (const float4*)(all_emis + (size_t)b * SS) + tid;
    float4 em = *emp;   // t=0

    // ---- priors log-softmax denominator ----
    float lm = fmaxf(fmaxf(pv.x, pv.y), fmaxf(pv.z, pv.w));
#pragma unroll
    for (int o = 32; o; o >>= 1) lm = fmaxf(lm, __shfl_xor(lm, o));
    if (lane == 0) pr[wid] = lm;
    __syncthreads();
    float gm = pr[0];
#pragma unroll
    for (int w = 1; w < 16; w++) gm = fmaxf(gm, pr[w]);
    __syncthreads();
    float ls = __expf(pv.x - gm) + __expf(pv.y - gm) + __expf(pv.z - gm) + __expf(pv.w - gm);
#pragma unroll
    for (int o = 32; o; o >>= 1) ls += __shfl_xor(ls, o);
    if (lane == 0) pr[wid] = ls;
    __syncthreads();
    float gs = 0.f;
#pragma unroll
    for (int w = 0; w < 16; w++) gs += pr[w];
    float logZp = gm + __logf(gs);

    // ---- step 0 (store deferred into loop) ----
    float v0 = em.x + pv.x - logZp;
    float v1 = em.y + pv.y - logZp;
    float v2 = em.z + pv.z - logZp;
    float v3 = em.w + pv.w - logZp;
    float4 ov_prev = {v0, v1, v2, v3};
    float4* outp = (float4*)(out + (size_t)b * SS) + tid;  // slot for t=0

    if (tid == 0) red2[0] = v0;   // g_0
    __syncthreads();
    float g1 = red2[0];
    float XpPrev = g1;
    float Erx = __expf(v0 - XpPrev), Ery = __expf(v1 - XpPrev);
    float Erz = __expf(v2 - XpPrev), Erw = __expf(v3 - XpPrev);
    {
        ushort4 E;
        E.x = f2b(Erx); E.y = f2b(Ery); E.z = f2b(Erz); E.w = f2b(Erw);
        *(ushort4*)(&Ebuf[0][GUARD_L + 4 * tid]) = E;
    }

    emp += (BB * SS) / 4;
    float4 em_next = *emp;   // t=1

    // ---- steps 1..L-1: one raw barrier per step; out-store one step behind ----
    int cur = 0;
    for (int t = 1; t < LL; t++) {
        BAR();
        *outp = ov_prev;                    // store v_{t-1}; ack never drained in-loop
        outp += (BB * SS) / 4;

        em = em_next;
        if (t < LL - 1) { emp += (BB * SS) / 4; em_next = *emp; }

        float g0 = red2[cur];
        float Xp = 2.f * g0 - g1;

        const unsigned short* Eb = Ebuf[cur] + GUARD_L + 4 * tid;
        ushort4 YpU = *(const ushort4*)(Eb + 16);
        ushort4 YmU = *(const ushort4*)(Eb - 16);
        ushort4 ZpU = *(const ushort4*)(Eb + 256);
        ushort4 ZqU = *(const ushort4*)(Eb + 512);
        float bx  = b2f(Eb[4]);
        float cxw = b2f(Eb[-1]);

        float a0 = Erx*pw[0]  + Ery*pw[1]  + cxw*pw[2]  + b2f(YpU.x)*pw[3]  + b2f(YmU.x)*pw[4]  + b2f(ZpU.x)*pw[5]  + b2f(ZqU.x)*pw[6];
        float a1 = Ery*pw[7]  + Erz*pw[8]  + Erx*pw[9]  + b2f(YpU.y)*pw[10] + b2f(YmU.y)*pw[11] + b2f(ZpU.y)*pw[12] + b2f(ZqU.y)*pw[13];
        float a2 = Erz*pw[14] + Erw*pw[15] + Ery*pw[16] + b2f(YpU.z)*pw[17] + b2f(YmU.z)*pw[18] + b2f(ZpU.z)*pw[19] + b2f(ZqU.z)*pw[20];
        float a3 = Erw*pw[21] + bx*pw[22]  + Erz*pw[23] + b2f(YpU.w)*pw[24] + b2f(YmU.w)*pw[25] + b2f(ZpU.w)*pw[26] + b2f(ZqU.w)*pw[27];

        v0 = em.x + __logf(a0) + XpPrev + am[0];
        v1 = em.y + __logf(a1) + XpPrev + am[1];
        v2 = em.z + __logf(a2) + XpPrev + am[2];
        v3 = em.w + __logf(a3) + XpPrev + am[3];
        ov_prev.x = v0; ov_prev.y = v1; ov_prev.z = v2; ov_prev.w = v3;

        Erx = __expf(v0 - Xp); Ery = __expf(v1 - Xp);
        Erz = __expf(v2 - Xp); Erw = __expf(v3 - Xp);
        {
            ushort4 E;
            E.x = f2b(Erx); E.y = f2b(Ery); E.z = f2b(Erz); E.w = f2b(Erw);
            *(ushort4*)(&Ebuf[cur ^ 1][GUARD_L + 4 * tid]) = E;
        }
        if (tid == 0) red2[cur ^ 1] = v0;  // g_t

        g1 = g0; XpPrev = Xp; cur ^= 1;
    }
    *outp = ov_prev;   // t = LL-1
}

extern "C" void kernel_launch(void* const* d_in, const int* in_sizes, int n_in,
                              void* d_out, int out_size, void* d_ws, size_t ws_size,
                              hipStream_t stream) {
    const int*   stories = (const int*)d_in[0];
    const float* trans_w = (const float*)d_in[2];
    const float* emis_w  = (const float*)d_in[3];
    const float* prior_w = (const float*)d_in[4];
    float* out = (float*)d_out;

    char* ws = (char*)d_ws;
    float* smT      = (float*)(ws);                                        // 32 MB
    float* all_emis = (float*)(ws + (size_t)VV * SS * 4);                  // 4 MB
    float* logZ     = (float*)(ws + (size_t)VV * SS * 4 + (size_t)LL * BB * SS * 4);  // 16 KB

    k_logZ<<<SS / 4, 256, 0, stream>>>(emis_w, logZ);
    k_smooth<<<dim3(ZD, VV / VC), 256, 0, stream>>>(emis_w, logZ, smT);
    k_emis<<<LL * BB, 256, 0, stream>>>(stories, smT, all_emis);
    k_forward<<<BB, 1024, 0, stream>>>(trans_w, prior_w, all_emis, out);
}